// Round 12
// baseline (35.040 us; speedup 1.0000x reference)
//
#include <hip/hip_runtime.h>
#include <hip/hip_bf16.h>
#include <math.h>

#define BEV_H 100
#define BEV_W 100
#define BEV_Z 4
#define N_CAM 6
#define C_DIM 256
#define H_IMG 32
#define W_IMG 88
#define NQ (BEV_H * BEV_W)
#define HW_IMG (H_IMG * W_IMG)   // 2816
#define QB 32
#define NBLK ((NQ + QB - 1) / QB)   // 313

typedef float f32x4 __attribute__((ext_vector_type(4)));
typedef short short8 __attribute__((ext_vector_type(8)));

__device__ __forceinline__ unsigned short f2b(float f) {
    __hip_bfloat16 h = __float2bfloat16(f);   // RNE
    return *reinterpret_cast<unsigned short*>(&h);
}
__device__ __forceinline__ float b2f_lo(unsigned int u) {   // low ushort -> f32
    return __uint_as_float(u << 16);
}
__device__ __forceinline__ float b2f_hi(unsigned int u) {   // high ushort -> f32
    return __uint_as_float(u & 0xffff0000u);
}

// Bijective XCD-chunked blockIdx swizzle (m204).
__device__ __forceinline__ int xcd_swz(int bid, int nwg) {
    int q = nwg >> 3, r = nwg & 7;
    int xcd = bid & 7;
    int idx = bid >> 3;
    int base = (xcd < r) ? xcd * (q + 1) : r * (q + 1) + (xcd - r) * q;
    return base + idx;
}

// ---------------- Kernel 1: img (cam,C,H,W) f32 -> imgT (cam,HW,C) bf16; z==6: Wout f32 -> bf16
__global__ __launch_bounds__(256) void prep_kernel(const float* __restrict__ img,
                                                   const float* __restrict__ Wout,
                                                   unsigned short* __restrict__ imgT,
                                                   unsigned short* __restrict__ Woutb) {
    int cam = blockIdx.z;
    int t = threadIdx.x;
    if (cam == N_CAM) {
        if (blockIdx.y == 0 && blockIdx.x < 64) {
            int base = (blockIdx.x * 256 + t) * 4;
            float4 v = *(const float4*)(Wout + base);
            ushort4 o;
            o.x = f2b(v.x); o.y = f2b(v.y); o.z = f2b(v.z); o.w = f2b(v.w);
            *(ushort4*)(Woutb + base) = o;
        }
        return;
    }
    __shared__ unsigned short tile[32][68];   // [hw][c], pad 68 keeps ushort4 reads clean
    int hw0 = blockIdx.x * 32;                // 88 blocks
    int c0  = blockIdx.y * 64;                // 4 blocks
    const float* src = img + (size_t)cam * C_DIM * HW_IMG;
    #pragma unroll
    for (int i = 0; i < 2; ++i) {
        int e = i * 256 + t;                  // 0..511
        int c  = e >> 3;                      // 0..63
        int hq = e & 7;                       // hw quad
        float4 v = *(const float4*)(src + (size_t)(c0 + c) * HW_IMG + hw0 + hq * 4);
        tile[hq * 4 + 0][c] = f2b(v.x);
        tile[hq * 4 + 1][c] = f2b(v.y);
        tile[hq * 4 + 2][c] = f2b(v.z);
        tile[hq * 4 + 3][c] = f2b(v.w);
    }
    __syncthreads();
    unsigned short* dst = imgT + (size_t)cam * HW_IMG * C_DIM;
    #pragma unroll
    for (int i = 0; i < 2; ++i) {
        int e = i * 256 + t;
        int hw = e >> 4;                      // 0..31
        int cq = e & 15;                      // c quad
        ushort4 o;
        o.x = tile[hw][cq * 4 + 0];
        o.y = tile[hw][cq * 4 + 1];
        o.z = tile[hw][cq * 4 + 2];
        o.w = tile[hw][cq * 4 + 3];
        *(ushort4*)(dst + (size_t)(hw0 + hw) * C_DIM + c0 + cq * 4) = o;
    }
}

// ---------------- Kernel 2 (fused): sample 32 queries into LDS A-tile, then
// MFMA GEMM vs Woutb, + bias + residual, store. No wbuf round-trip, no
// kernel-boundary barrier between sampling and GEMM.
__global__ __launch_bounds__(256) void fused_kernel(const unsigned short* __restrict__ imgT,
                                                    const float* __restrict__ l2i,
                                                    const unsigned short* __restrict__ Woutb,
                                                    const float* __restrict__ bout,
                                                    const float* __restrict__ query,
                                                    float* __restrict__ out) {
    __shared__ int   ent_off[QB][24][4];          // 12 KB
    __shared__ float ent_w[QB][24][4];            // 12 KB
    __shared__ int   counts[QB];
    __shared__ unsigned short Atile[QB * C_DIM];  // 16 KB, swizzled byte^=(row&7)<<4
    __shared__ unsigned short Btile[64 * C_DIM];  // 32 KB, swizzled
    int t = threadIdx.x;
    int blk = xcd_swz(blockIdx.x, NBLK);
    int qbase = blk * QB;

    // ---- phase 1: projection for 32 queries x 24 slots (4 passes of 8 q)
    #pragma unroll
    for (int pass = 0; pass < 4; ++pass) {
        int ql   = pass * 8 + (t >> 5);   // 0..31
        int slot = t & 31;
        int q = qbase + ql;
        int ix = q % BEV_W;
        int iy = q / BEV_W;
        float x = ((ix + 0.5f) / (float)BEV_W) * 102.4f - 51.2f;
        float y = ((iy + 0.5f) / (float)BEV_H) * 102.4f - 51.2f;

        bool valid = false;
        int   o0 = 0, o1 = 0, o2 = 0, o3 = 0;
        float w0 = 0.f, w1 = 0.f, w2 = 0.f, w3 = 0.f;
        if (slot < 24 && q < NQ) {
            int cam = slot >> 2;
            int zi  = slot & 3;
            const float* L = l2i + cam * 16;
            float zl = (zi + 0.5f) * 8.0f - 5.0f;   // reference's unnormalized z
            float cx = fmaf(L[0], x, fmaf(L[1], y, fmaf(L[2],  zl, L[3])));
            float cy = fmaf(L[4], x, fmaf(L[5], y, fmaf(L[6],  zl, L[7])));
            float cz = fmaf(L[8], x, fmaf(L[9], y, fmaf(L[10], zl, L[11])));
            float denom = fmaxf(cz, 1e-5f);
            float inv = __builtin_amdgcn_rcpf(denom);
            float u = cx * inv;
            float v = cy * inv;
            if ((cz > 1e-5f) && (u > 0.f) && (u < (float)W_IMG)
                             && (v > 0.f) && (v < (float)H_IMG)) {
                valid = true;
                float xs = u - 0.5f;    // == (gx+1)*W/2 - 0.5 exactly
                float ys = v - 0.5f;
                float x0f = floorf(xs), y0f = floorf(ys);
                float wx1 = xs - x0f,   wy1 = ys - y0f;
                float wx0 = 1.0f - wx1, wy0 = 1.0f - wy1;
                int x0 = (int)x0f, y0 = (int)y0f;   // x0 in [-1,87], y0 in [-1,31]
                int x1 = x0 + 1,   y1 = y0 + 1;
                float mxl = (x0 >= 0)     ? 1.f : 0.f;
                float mxh = (x1 < W_IMG)  ? 1.f : 0.f;
                float myl = (y0 >= 0)     ? 1.f : 0.f;
                float myh = (y1 < H_IMG)  ? 1.f : 0.f;
                int x0c = max(x0, 0), x1c = min(x1, W_IMG - 1);
                int y0c = max(y0, 0), y1c = min(y1, H_IMG - 1);
                int cbase = cam * HW_IMG;
                // byte offsets into imgT (row stride C_DIM*2 = 512 = <<9)
                o0 = (cbase + y0c * W_IMG + x0c) << 9;  w0 = (wx0 * mxl) * (wy0 * myl);
                o1 = (cbase + y0c * W_IMG + x1c) << 9;  w1 = (wx1 * mxh) * (wy0 * myl);
                o2 = (cbase + y1c * W_IMG + x0c) << 9;  w2 = (wx0 * mxl) * (wy1 * myh);
                o3 = (cbase + y1c * W_IMG + x1c) << 9;  w3 = (wx1 * mxh) * (wy1 * myh);
            }
        }
        unsigned long long bal = __ballot(valid);
        unsigned int half = (t & 32) ? (unsigned int)(bal >> 32) : (unsigned int)bal;
        int lane32 = t & 31;
        int pre = __popc(half & ((1u << lane32) - 1u));
        if (valid) {
            ent_off[ql][pre][0] = o0; ent_off[ql][pre][1] = o1;
            ent_off[ql][pre][2] = o2; ent_off[ql][pre][3] = o3;
            ent_w[ql][pre][0] = w0; ent_w[ql][pre][1] = w1;
            ent_w[ql][pre][2] = w2; ent_w[ql][pre][3] = w3;
        }
        if (lane32 == 0) counts[ql] = __popc(half);
    }
    __syncthreads();

    // ---- phase 2: gather; each half-wave serves 4 queries -> LDS A-tile rows
    {
        int hw = t >> 5;
        int lane32 = t & 31;
        const char* base = (const char*)imgT + lane32 * 16;   // 8 ch/lane
        #pragma unroll
        for (int p = 0; p < 4; ++p) {
            int ql = p * 8 + hw;
            int cnt = counts[ql];
            float a0 = 0.f, a1 = 0.f, a2 = 0.f, a3 = 0.f;
            float a4 = 0.f, a5 = 0.f, a6 = 0.f, a7 = 0.f;
            for (int i = 0; i < cnt; ++i) {
                int4   offs = *(const int4*)(&ent_off[ql][i][0]);
                float4 wv   = *(const float4*)(&ent_w[ql][i][0]);
                int4 f0 = *(const int4*)(base + offs.x);
                int4 f1 = *(const int4*)(base + offs.y);
                int4 f2 = *(const int4*)(base + offs.z);
                int4 f3 = *(const int4*)(base + offs.w);
                a0 += b2f_lo(f0.x) * wv.x; a1 += b2f_hi(f0.x) * wv.x;
                a2 += b2f_lo(f0.y) * wv.x; a3 += b2f_hi(f0.y) * wv.x;
                a4 += b2f_lo(f0.z) * wv.x; a5 += b2f_hi(f0.z) * wv.x;
                a6 += b2f_lo(f0.w) * wv.x; a7 += b2f_hi(f0.w) * wv.x;
                a0 += b2f_lo(f1.x) * wv.y; a1 += b2f_hi(f1.x) * wv.y;
                a2 += b2f_lo(f1.y) * wv.y; a3 += b2f_hi(f1.y) * wv.y;
                a4 += b2f_lo(f1.z) * wv.y; a5 += b2f_hi(f1.z) * wv.y;
                a6 += b2f_lo(f1.w) * wv.y; a7 += b2f_hi(f1.w) * wv.y;
                a0 += b2f_lo(f2.x) * wv.z; a1 += b2f_hi(f2.x) * wv.z;
                a2 += b2f_lo(f2.y) * wv.z; a3 += b2f_hi(f2.y) * wv.z;
                a4 += b2f_lo(f2.z) * wv.z; a5 += b2f_hi(f2.z) * wv.z;
                a6 += b2f_lo(f2.w) * wv.z; a7 += b2f_hi(f2.w) * wv.z;
                a0 += b2f_lo(f3.x) * wv.w; a1 += b2f_hi(f3.x) * wv.w;
                a2 += b2f_lo(f3.y) * wv.w; a3 += b2f_hi(f3.y) * wv.w;
                a4 += b2f_lo(f3.z) * wv.w; a5 += b2f_hi(f3.z) * wv.w;
                a6 += b2f_lo(f3.w) * wv.w; a7 += b2f_hi(f3.w) * wv.w;
            }
            const float s = 1.0f / 24.0f;
            int4 o;
            o.x = (int)f2b(a0 * s) | ((int)f2b(a1 * s) << 16);
            o.y = (int)f2b(a2 * s) | ((int)f2b(a3 * s) << 16);
            o.z = (int)f2b(a4 * s) | ((int)f2b(a5 * s) << 16);
            o.w = (int)f2b(a6 * s) | ((int)f2b(a7 * s) << 16);
            int off = (ql * 512 + lane32 * 16) ^ ((ql & 7) << 4);
            *(int4*)((char*)Atile + off) = o;
        }
    }
    __syncthreads();

    // ---- phase 3: GEMM 32x256 = Atile @ Woutb^T, 4 col-tiles of 64
    int lane = t & 63;
    int wid = t >> 6;
    int fr = lane & 15;
    int kq = lane >> 4;
    int crow = kq * 4;
    int ccol = fr;

    for (int cb = 0; cb < C_DIM; cb += 64) {
        // stage B: 64 cols x 256 k bf16 = 2048 x 16B chunks
        #pragma unroll
        for (int i = 0; i < 8; ++i) {
            int idx = i * 256 + t;
            int row = idx >> 5;            // 0..63
            int ch  = idx & 31;            // 16B chunk within 512B row
            int4 bv = *(const int4*)(Woutb + (size_t)(cb + row) * C_DIM + ch * 8);
            int off = (row * 512 + ch * 16) ^ ((row & 7) << 4);
            *(int4*)((char*)Btile + off) = bv;
        }
        __syncthreads();

        f32x4 acc0 = {}, acc1 = {};
        #pragma unroll
        for (int ks = 0; ks < 8; ++ks) {
            int kbyte = ks * 64 + kq * 16;
            int m0 = fr, m1 = fr + 16;
            int n = wid * 16 + fr;
            short8 af0 = *(const short8*)((const char*)Atile + ((m0 * 512 + kbyte) ^ ((m0 & 7) << 4)));
            short8 af1 = *(const short8*)((const char*)Atile + ((m1 * 512 + kbyte) ^ ((m1 & 7) << 4)));
            short8 bf  = *(const short8*)((const char*)Btile + ((n  * 512 + kbyte) ^ ((n  & 7) << 4)));
            acc0 = __builtin_amdgcn_mfma_f32_16x16x32_bf16(af0, bf, acc0, 0, 0, 0);
            acc1 = __builtin_amdgcn_mfma_f32_16x16x32_bf16(af1, bf, acc1, 0, 0, 0);
        }

        // store this col-tile (C/D layout: col=lane&15, row=(lane>>4)*4+reg)
        int nn = cb + wid * 16 + ccol;
        float bn = bout[nn];
        #pragma unroll
        for (int fi = 0; fi < 2; ++fi) {
            f32x4 a = fi ? acc1 : acc0;
            #pragma unroll
            for (int r = 0; r < 4; ++r) {
                int m = qbase + fi * 16 + crow + r;
                if (m < NQ) {
                    size_t off = (size_t)m * C_DIM + nn;
                    out[off] = a[r] + bn + query[off];
                }
            }
        }
        __syncthreads();   // before next B staging overwrites Btile
    }
}

extern "C" void kernel_launch(void* const* d_in, const int* in_sizes, int n_in,
                              void* d_out, int out_size, void* d_ws, size_t ws_size,
                              hipStream_t stream) {
    const float* query = (const float*)d_in[0];   // (1, 10000, 256)
    const float* img   = (const float*)d_in[1];   // (1, 6, 256, 32, 88)
    const float* l2i   = (const float*)d_in[2];   // (1, 6, 4, 4)
    const float* Wout  = (const float*)d_in[3];   // (256, 256)
    const float* bout  = (const float*)d_in[4];   // (256,)
    float* out = (float*)d_out;

    // workspace layout (16B aligned)
    unsigned short* imgT  = (unsigned short*)d_ws;                      // 6*2816*256*2 = 8,650,752 B
    unsigned short* Woutb = (unsigned short*)((char*)d_ws + 8650752);   // 256*256*2    =   131,072 B

    dim3 gP(HW_IMG / 32, C_DIM / 64, N_CAM + 1);   // (88, 4, 7); z==6 converts Wout
    prep_kernel<<<gP, 256, 0, stream>>>(img, Wout, imgT, Woutb);

    fused_kernel<<<NBLK, 256, 0, stream>>>(imgT, l2i, Woutb, bout, query, out);
}

// Round 13
// 27.823 us; speedup vs baseline: 1.2594x; 1.2594x over previous
//
#include <hip/hip_runtime.h>
#include <hip/hip_bf16.h>
#include <math.h>

#define BEV_H 100
#define BEV_W 100
#define BEV_Z 4
#define N_CAM 6
#define C_DIM 256
#define H_IMG 32
#define W_IMG 88
#define NQ (BEV_H * BEV_W)
#define HW_IMG (H_IMG * W_IMG)   // 2816

typedef float f32x4 __attribute__((ext_vector_type(4)));
typedef short short8 __attribute__((ext_vector_type(8)));

__device__ __forceinline__ unsigned short f2b(float f) {
    __hip_bfloat16 h = __float2bfloat16(f);   // RNE
    return *reinterpret_cast<unsigned short*>(&h);
}
__device__ __forceinline__ float b2f_lo(unsigned int u) {   // low ushort -> f32
    return __uint_as_float(u << 16);
}
__device__ __forceinline__ float b2f_hi(unsigned int u) {   // high ushort -> f32
    return __uint_as_float(u & 0xffff0000u);
}

// Bijective XCD-chunked blockIdx swizzle (m204): consecutive returned ids are
// processed by the same XCD (dispatch round-robins blockIdx across 8 XCDs).
__device__ __forceinline__ int xcd_swz(int bid, int nwg) {
    int q = nwg >> 3, r = nwg & 7;
    int xcd = bid & 7;
    int idx = bid >> 3;
    int base = (xcd < r) ? xcd * (q + 1) : r * (q + 1) + (xcd - r) * q;
    return base + idx;
}

// ---------------- Kernel 1: img (cam,C,H,W) f32 -> imgT (cam,HW,C) bf16; z==6: Wout f32 -> bf16
__global__ __launch_bounds__(256) void prep_kernel(const float* __restrict__ img,
                                                   const float* __restrict__ Wout,
                                                   unsigned short* __restrict__ imgT,
                                                   unsigned short* __restrict__ Woutb) {
    int cam = blockIdx.z;
    int t = threadIdx.x;
    if (cam == N_CAM) {
        if (blockIdx.y == 0 && blockIdx.x < 64) {
            int base = (blockIdx.x * 256 + t) * 4;
            float4 v = *(const float4*)(Wout + base);
            ushort4 o;
            o.x = f2b(v.x); o.y = f2b(v.y); o.z = f2b(v.z); o.w = f2b(v.w);
            *(ushort4*)(Woutb + base) = o;
        }
        return;
    }
    __shared__ unsigned short tile[32][68];   // [hw][c], pad 68 keeps ushort4 reads clean
    int hw0 = blockIdx.x * 32;                // 88 blocks
    int c0  = blockIdx.y * 64;                // 4 blocks
    const float* src = img + (size_t)cam * C_DIM * HW_IMG;
    #pragma unroll
    for (int i = 0; i < 2; ++i) {
        int e = i * 256 + t;                  // 0..511
        int c  = e >> 3;                      // 0..63
        int hq = e & 7;                       // hw quad
        float4 v = *(const float4*)(src + (size_t)(c0 + c) * HW_IMG + hw0 + hq * 4);
        tile[hq * 4 + 0][c] = f2b(v.x);
        tile[hq * 4 + 1][c] = f2b(v.y);
        tile[hq * 4 + 2][c] = f2b(v.z);
        tile[hq * 4 + 3][c] = f2b(v.w);
    }
    __syncthreads();
    unsigned short* dst = imgT + (size_t)cam * HW_IMG * C_DIM;
    #pragma unroll
    for (int i = 0; i < 2; ++i) {
        int e = i * 256 + t;
        int hw = e >> 4;                      // 0..31
        int cq = e & 15;                      // c quad
        ushort4 o;
        o.x = tile[hw][cq * 4 + 0];
        o.y = tile[hw][cq * 4 + 1];
        o.z = tile[hw][cq * 4 + 2];
        o.w = tile[hw][cq * 4 + 3];
        *(ushort4*)(dst + (size_t)(hw0 + hw) * C_DIM + c0 + cq * 4) = o;
    }
}

// ---------------- Kernel 2: project + bilinear + pool, two-phase, 8 queries/block.
// Phase 2 accumulation vectorized as f32x4 (v_pk_fma_f32 candidates).
__global__ __launch_bounds__(256) void sample_kernel(const unsigned short* __restrict__ imgT,
                                                     const float* __restrict__ l2i,
                                                     unsigned short* __restrict__ wbuf) {
    __shared__ int   ent_off[8][24][4];
    __shared__ float ent_w[8][24][4];
    __shared__ int   counts[8];
    int t = threadIdx.x;
    int blk = xcd_swz(blockIdx.x, NQ / 8);   // 1250 blocks

    {
        int ql   = t >> 5;        // 0..7
        int slot = t & 31;        // 0..31; slots 24..31 padding
        int q = blk * 8 + ql;
        int ix = q % BEV_W;
        int iy = q / BEV_W;
        float x = ((ix + 0.5f) / (float)BEV_W) * 102.4f - 51.2f;
        float y = ((iy + 0.5f) / (float)BEV_H) * 102.4f - 51.2f;

        bool valid = false;
        int   o0 = 0, o1 = 0, o2 = 0, o3 = 0;
        float w0 = 0.f, w1 = 0.f, w2 = 0.f, w3 = 0.f;
        if (slot < 24) {
            int cam = slot >> 2;
            int zi  = slot & 3;
            const float* L = l2i + cam * 16;
            float zl = (zi + 0.5f) * 8.0f - 5.0f;   // reference's unnormalized z
            float cx = fmaf(L[0], x, fmaf(L[1], y, fmaf(L[2],  zl, L[3])));
            float cy = fmaf(L[4], x, fmaf(L[5], y, fmaf(L[6],  zl, L[7])));
            float cz = fmaf(L[8], x, fmaf(L[9], y, fmaf(L[10], zl, L[11])));
            float denom = fmaxf(cz, 1e-5f);
            float inv = __builtin_amdgcn_rcpf(denom);
            float u = cx * inv;
            float v = cy * inv;
            if ((cz > 1e-5f) && (u > 0.f) && (u < (float)W_IMG)
                             && (v > 0.f) && (v < (float)H_IMG)) {
                valid = true;
                float xs = u - 0.5f;    // == (gx+1)*W/2 - 0.5 exactly
                float ys = v - 0.5f;
                float x0f = floorf(xs), y0f = floorf(ys);
                float wx1 = xs - x0f,   wy1 = ys - y0f;
                float wx0 = 1.0f - wx1, wy0 = 1.0f - wy1;
                int x0 = (int)x0f, y0 = (int)y0f;   // x0 in [-1,87], y0 in [-1,31]
                int x1 = x0 + 1,   y1 = y0 + 1;
                float mxl = (x0 >= 0)     ? 1.f : 0.f;
                float mxh = (x1 < W_IMG)  ? 1.f : 0.f;
                float myl = (y0 >= 0)     ? 1.f : 0.f;
                float myh = (y1 < H_IMG)  ? 1.f : 0.f;
                int x0c = max(x0, 0), x1c = min(x1, W_IMG - 1);
                int y0c = max(y0, 0), y1c = min(y1, H_IMG - 1);
                int cbase = cam * HW_IMG;
                // byte offsets into imgT (row stride C_DIM*2 = 512 = <<9)
                o0 = (cbase + y0c * W_IMG + x0c) << 9;  w0 = (wx0 * mxl) * (wy0 * myl);
                o1 = (cbase + y0c * W_IMG + x1c) << 9;  w1 = (wx1 * mxh) * (wy0 * myl);
                o2 = (cbase + y1c * W_IMG + x0c) << 9;  w2 = (wx0 * mxl) * (wy1 * myh);
                o3 = (cbase + y1c * W_IMG + x1c) << 9;  w3 = (wx1 * mxh) * (wy1 * myh);
            }
        }
        unsigned long long bal = __ballot(valid);
        unsigned int half = (t & 32) ? (unsigned int)(bal >> 32) : (unsigned int)bal;
        int lane32 = t & 31;
        int pre = __popc(half & ((1u << lane32) - 1u));
        if (valid) {
            ent_off[ql][pre][0] = o0; ent_off[ql][pre][1] = o1;
            ent_off[ql][pre][2] = o2; ent_off[ql][pre][3] = o3;
            ent_w[ql][pre][0] = w0; ent_w[ql][pre][1] = w1;
            ent_w[ql][pre][2] = w2; ent_w[ql][pre][3] = w3;
        }
        if (lane32 == 0) counts[ql] = __popc(half);
    }
    __syncthreads();

    int qi = t >> 5;               // 0..7: half-wave index == query index
    int lane32 = t & 31;
    int q = blk * 8 + qi;
    int cnt = counts[qi];
    const char* base = (const char*)imgT + lane32 * 16;   // 8 channels/lane

    f32x4 accL = {0.f, 0.f, 0.f, 0.f};   // channels {0,2,4,6} (low halves)
    f32x4 accH = {0.f, 0.f, 0.f, 0.f};   // channels {1,3,5,7} (high halves)
    for (int i = 0; i < cnt; ++i) {   // divergent between halves; exec-masked
        int4   offs = *(const int4*)(&ent_off[qi][i][0]);    // broadcast/half
        float4 wv   = *(const float4*)(&ent_w[qi][i][0]);
        int4 f0 = *(const int4*)(base + offs.x);
        int4 f1 = *(const int4*)(base + offs.y);
        int4 f2 = *(const int4*)(base + offs.z);
        int4 f3 = *(const int4*)(base + offs.w);
        {
            f32x4 lo = {b2f_lo(f0.x), b2f_lo(f0.y), b2f_lo(f0.z), b2f_lo(f0.w)};
            f32x4 hi = {b2f_hi(f0.x), b2f_hi(f0.y), b2f_hi(f0.z), b2f_hi(f0.w)};
            accL += lo * wv.x; accH += hi * wv.x;
        }
        {
            f32x4 lo = {b2f_lo(f1.x), b2f_lo(f1.y), b2f_lo(f1.z), b2f_lo(f1.w)};
            f32x4 hi = {b2f_hi(f1.x), b2f_hi(f1.y), b2f_hi(f1.z), b2f_hi(f1.w)};
            accL += lo * wv.y; accH += hi * wv.y;
        }
        {
            f32x4 lo = {b2f_lo(f2.x), b2f_lo(f2.y), b2f_lo(f2.z), b2f_lo(f2.w)};
            f32x4 hi = {b2f_hi(f2.x), b2f_hi(f2.y), b2f_hi(f2.z), b2f_hi(f2.w)};
            accL += lo * wv.z; accH += hi * wv.z;
        }
        {
            f32x4 lo = {b2f_lo(f3.x), b2f_lo(f3.y), b2f_lo(f3.z), b2f_lo(f3.w)};
            f32x4 hi = {b2f_hi(f3.x), b2f_hi(f3.y), b2f_hi(f3.z), b2f_hi(f3.w)};
            accL += lo * wv.w; accH += hi * wv.w;
        }
    }
    const float s = 1.0f / 24.0f;
    int4 o;
    o.x = (int)f2b(accL[0] * s) | ((int)f2b(accH[0] * s) << 16);
    o.y = (int)f2b(accL[1] * s) | ((int)f2b(accH[1] * s) << 16);
    o.z = (int)f2b(accL[2] * s) | ((int)f2b(accH[2] * s) << 16);
    o.w = (int)f2b(accL[3] * s) | ((int)f2b(accH[3] * s) << 16);
    *(int4*)(wbuf + (size_t)q * C_DIM + lane32 * 8) = o;
}

// ---------------- Kernel 3: out = w @ Wout^T + b + query, bf16 MFMA 16x16x32
// 1-D grid 628 = 157 row-tiles x 4 col-tiles (row-major), XCD-chunked swizzle
// so the 4 col-tiles of a row-tile land on one XCD (A-row L2 reuse).
#define BM 64
#define BN 64
#define BKK 128
__global__ __launch_bounds__(256) void gemm_kernel(const unsigned short* __restrict__ A,   // wbuf bf16 (NQ x 256)
                                                   const unsigned short* __restrict__ B,   // Woutb bf16 (256 x 256)
                                                   const float* __restrict__ bout,
                                                   const float* __restrict__ query,
                                                   float* __restrict__ out) {
    __shared__ unsigned short Al[BM * BKK];   // 16 KB, swizzled: byte ^= (row&7)<<4
    __shared__ unsigned short Bl[BN * BKK];   // 16 KB
    int blk = xcd_swz(blockIdx.x, 157 * 4);
    int rb = (blk >> 2) * BM;
    int cb = (blk & 3) * BN;
    int t = threadIdx.x;
    int lane = t & 63;
    int wid = t >> 6;
    int wr = wid >> 1, wc = wid & 1;
    int fr = lane & 15;
    int kq = lane >> 4;                       // 0..3: k-group within K=32

    f32x4 acc[2][2] = {};

    for (int kt = 0; kt < C_DIM; kt += BKK) {
        // stage A + B: 64 rows x 128 k (bf16) = 1024 x 16B chunks each
        #pragma unroll
        for (int i = 0; i < 4; ++i) {
            int idx = i * 256 + t;            // 0..1023
            int row = idx >> 4;               // 0..63
            int ch  = idx & 15;               // 16B chunk within 256B row
            int4 av = make_int4(0, 0, 0, 0);
            int grow = rb + row;
            if (grow < NQ) av = *(const int4*)(A + (size_t)grow * C_DIM + kt + ch * 8);
            int4 bv = *(const int4*)(B + (size_t)(cb + row) * C_DIM + kt + ch * 8);
            int off = (row * 256 + ch * 16) ^ ((row & 7) << 4);
            *(int4*)((char*)Al + off) = av;
            *(int4*)((char*)Bl + off) = bv;
        }
        __syncthreads();

        #pragma unroll
        for (int ks = 0; ks < 4; ++ks) {
            int kbyte = ks * 64 + kq * 16;
            int ra0 = wr * 32 + fr, ra1 = ra0 + 16;
            int rb0 = wc * 32 + fr, rb1 = rb0 + 16;
            short8 af0 = *(const short8*)((const char*)Al + ((ra0 * 256 + kbyte) ^ ((ra0 & 7) << 4)));
            short8 af1 = *(const short8*)((const char*)Al + ((ra1 * 256 + kbyte) ^ ((ra1 & 7) << 4)));
            short8 bf0 = *(const short8*)((const char*)Bl + ((rb0 * 256 + kbyte) ^ ((rb0 & 7) << 4)));
            short8 bf1 = *(const short8*)((const char*)Bl + ((rb1 * 256 + kbyte) ^ ((rb1 & 7) << 4)));
            acc[0][0] = __builtin_amdgcn_mfma_f32_16x16x32_bf16(af0, bf0, acc[0][0], 0, 0, 0);
            acc[0][1] = __builtin_amdgcn_mfma_f32_16x16x32_bf16(af0, bf1, acc[0][1], 0, 0, 0);
            acc[1][0] = __builtin_amdgcn_mfma_f32_16x16x32_bf16(af1, bf0, acc[1][0], 0, 0, 0);
            acc[1][1] = __builtin_amdgcn_mfma_f32_16x16x32_bf16(af1, bf1, acc[1][1], 0, 0, 0);
        }
        __syncthreads();
    }

    // C/D layout (verified m89/m91): col = lane&15, row = (lane>>4)*4 + reg
    int crow = (lane >> 4) * 4;
    int ccol = lane & 15;
    #pragma unroll
    for (int fi = 0; fi < 2; ++fi) {
        #pragma unroll
        for (int fj = 0; fj < 2; ++fj) {
            int n = cb + wc * 32 + fj * 16 + ccol;
            float bn = bout[n];
            #pragma unroll
            for (int r = 0; r < 4; ++r) {
                int m = rb + wr * 32 + fi * 16 + crow + r;
                if (m < NQ) {
                    size_t off = (size_t)m * C_DIM + n;
                    out[off] = acc[fi][fj][r] + bn + query[off];
                }
            }
        }
    }
}

extern "C" void kernel_launch(void* const* d_in, const int* in_sizes, int n_in,
                              void* d_out, int out_size, void* d_ws, size_t ws_size,
                              hipStream_t stream) {
    const float* query = (const float*)d_in[0];   // (1, 10000, 256)
    const float* img   = (const float*)d_in[1];   // (1, 6, 256, 32, 88)
    const float* l2i   = (const float*)d_in[2];   // (1, 6, 4, 4)
    const float* Wout  = (const float*)d_in[3];   // (256, 256)
    const float* bout  = (const float*)d_in[4];   // (256,)
    float* out = (float*)d_out;

    // workspace layout (16B aligned)
    unsigned short* imgT  = (unsigned short*)d_ws;                       // 6*2816*256*2 = 8,650,752 B
    unsigned short* wbuf  = (unsigned short*)((char*)d_ws + 8650752);    // 10000*256*2  = 5,120,000 B
    unsigned short* Woutb = (unsigned short*)((char*)d_ws + 13770752);   // 256*256*2    =   131,072 B

    dim3 gP(HW_IMG / 32, C_DIM / 64, N_CAM + 1);   // (88, 4, 7); z==6 converts Wout
    prep_kernel<<<gP, 256, 0, stream>>>(img, Wout, imgT, Woutb);

    sample_kernel<<<NQ / 8, 256, 0, stream>>>(imgT, l2i, wbuf);   // 1250 blocks

    gemm_kernel<<<157 * 4, 256, 0, stream>>>(wbuf, Woutb, bout, query, out);
}